// Round 10
// baseline (340.184 us; speedup 1.0000x reference)
//
#include <hip/hip_runtime.h>
#include <hip/hip_bf16.h>

#define NUSERS 60000
#define NNODES 100000
#define DD 64
#define NGB 1563  // ceil(NNODES/64) — 64-row tiles
#define GMM 782   // k_mm4 grid: exactly 2 tiles per block (balanced)
#define NBUK 196  // ceil(NNODES/512) coarse buckets (dst>>9)
#define ESB 2048  // edges per k_bscatter block
#define NBH 400   // k_bhist blocks (partial-hist rows)
#define NSH 64    // reduction shards (6250 blocks / 64 ≈ 98 adds/address)

typedef __hip_bfloat16 bf16;
using bf16x8 = __attribute__((ext_vector_type(8))) short;
using f32x4  = __attribute__((ext_vector_type(4))) float;

__device__ __forceinline__ float b2f(bf16 x) { return __bfloat162float(x); }
__device__ __forceinline__ bf16 f2b(float x) { return __float2bfloat16(x); }
// NOTE (round-6 lesson): do NOT replace with v_cvt_pk_bf16_f32 inline asm.
// Produced absmax=237 (scrambled T halves). __float2bfloat16 is the
// proven-correct path.
__device__ __forceinline__ unsigned short fbits(float x) {
    union { bf16 b; unsigned short u; } cv; cv.b = f2b(x); return cv.u;
}
__device__ __forceinline__ float us2f(unsigned short h) {
    union { unsigned u; float f; } t; t.u = (unsigned)h << 16; return t.f;
}
__device__ __forceinline__ float lo_bf16(unsigned w) {
    union { unsigned u; float f; } t; t.u = w << 16; return t.f;
}
__device__ __forceinline__ float hi_bf16(unsigned w) {
    union { unsigned u; float f; } t; t.u = w & 0xFFFF0000u; return t.f;
}
__device__ __forceinline__ float ldf(const void* p, size_t i, int isbf) {
    if (isbf) return b2f(((const bf16*)p)[i]);
    return ((const float*)p)[i];
}
__device__ __forceinline__ unsigned pack2(float a, float b) {
    return (unsigned)fbits(a) | ((unsigned)fbits(b) << 16);
}
__device__ __forceinline__ unsigned pr2(float x0, float x1, float a0, float a1,
                                        float b0, float b1) {
    float t0 = a0 * x0 + b0, t1 = a1 * x1 + b1;
    t0 = t0 > 0.f ? t0 : 0.f;
    t1 = t1 > 0.f ? t1 : 0.f;
    return pack2(t0, t1);
}

// ---- CSR build step 1 (+ fused dtype sniff in block 0). Round-7 proven.
__global__ __launch_bounds__(256) void k_bhist(
    const int* __restrict__ ee, const unsigned short* __restrict__ hsn,
    int* __restrict__ flag, int* __restrict__ bh, int E)
{
    __shared__ int h[256];
    int t = threadIdx.x;
    if (blockIdx.x == 0) {
        int cnt = 0;
        for (int i = t; i < 1024; i += 256) {
            int e = (hsn[2 * i] >> 7) & 0xFF;
            cnt += (e >= 100 && e <= 140) ? 1 : 0;
        }
        h[t] = cnt;
        __syncthreads();
        for (int s = 128; s > 0; s >>= 1) {
            if (t < s) h[t] += h[t + s];
            __syncthreads();
        }
        if (t == 0) flag[0] = (h[0] > 512) ? 1 : 0;
        __syncthreads();
    }
    h[t] = 0;
    __syncthreads();
    for (int e = blockIdx.x * 256 + t; e < E; e += gridDim.x * 256)
        atomicAdd(&h[ee[e] >> 9], 1);
    __syncthreads();
    bh[blockIdx.x * 256 + t] = h[t];
}

// Sum partial hists (4-way row-parallel, 1024 threads) -> scan ->
// bbase/bcursor. Also zeroes the sharded reduction counters.
// NOTE: no bbase[256] write — would alias bcursor[0].
__global__ __launch_bounds__(1024) void k_bscan(
    const int* __restrict__ bh, int* __restrict__ bbase,
    int* __restrict__ bcursor, float* __restrict__ redz)
{
    __shared__ int ps[1024];
    __shared__ int sd[256];
    int t = threadIdx.x;
    int col = t & 255, seg = t >> 8;       // 4 segments x 100 rows
    int v = 0;
#pragma unroll 4
    for (int b = seg * 100; b < (seg + 1) * 100; b++)
        v += bh[b * 256 + col];
    ps[t] = v;
    __syncthreads();
    int vv = 0;
    if (t < 256) {
        vv = ps[t] + ps[t + 256] + ps[t + 512] + ps[t + 768];
        sd[t] = vv;
    }
    __syncthreads();
    for (int off = 1; off < 256; off <<= 1) {
        int x = (t >= off && t < 256) ? sd[t - off] : 0;
        __syncthreads();
        if (t < 256) sd[t] += x;
        __syncthreads();
    }
    if (t < 256) {
        int excl = sd[t] - vv;
        bbase[t] = excl;
        bcursor[t] = excl;
    }
    for (int i = t; i < 2 * NSH * 256; i += 1024) redz[i] = 0.f;
}

// Entry = (dst&511)<<20 | src  (src < 2^17). Atomic bcursor allocation
// (round-7 proven): order within bucket is irrelevant — k_group re-orders
// per-node via its own cursors.
__global__ __launch_bounds__(256) void k_bscatter(
    const int* __restrict__ es, const int* __restrict__ ee,
    int* __restrict__ bcursor, unsigned* __restrict__ ebuf, int E)
{
    __shared__ int h[256], gb[256], lr[256];
    int t = threadIdx.x;
    h[t] = 0;
    lr[t] = 0;
    __syncthreads();
    int base = blockIdx.x * ESB;
    unsigned ent[8];
    int bk[8];
#pragma unroll
    for (int i = 0; i < 8; i++) {
        int e = base + t + i * 256;
        if (e < E) {
            int s = es[e], d = ee[e];
            bk[i] = d >> 9;
            ent[i] = (unsigned)s | ((unsigned)(d & 511) << 20);
            atomicAdd(&h[bk[i]], 1);
        } else bk[i] = -1;
    }
    __syncthreads();
    if (h[t]) gb[t] = atomicAdd(&bcursor[t], h[t]);
    __syncthreads();
#pragma unroll
    for (int i = 0; i < 8; i++) {
        if (bk[i] >= 0) {
            int r = atomicAdd(&lr[bk[i]], 1);
            ebuf[gb[bk[i]] + r] = ent[i];
        }
    }
}

__global__ __launch_bounds__(256) void k_group(
    const int* __restrict__ bbase, const unsigned* __restrict__ ebuf,
    int* __restrict__ rowptr, int* __restrict__ srcidx)
{
    __shared__ int h[512], sc[512];
    int b = blockIdx.x, t = threadIdx.x;
    int lo = bbase[b], hi = bbase[b + 1];
    h[t] = 0;
    h[t + 256] = 0;
    __syncthreads();
    for (int i = lo + t; i < hi; i += 256)
        atomicAdd(&h[ebuf[i] >> 20], 1);
    __syncthreads();
    sc[t] = h[t];
    sc[t + 256] = h[t + 256];
    __syncthreads();
    for (int off = 1; off < 512; off <<= 1) {
        int v0 = (t >= off) ? sc[t - off] : 0;
        int v1 = (t + 256 >= off) ? sc[t + 256 - off] : 0;
        __syncthreads();
        sc[t] += v0;
        sc[t + 256] += v1;
        __syncthreads();
    }
    int n0 = b * 512 + t, n1 = b * 512 + t + 256;
    int e0 = lo + sc[t] - h[t];
    int e1 = lo + sc[t + 256] - h[t + 256];
    if (n0 < NNODES) rowptr[n0] = e0;
    if (n1 < NNODES) rowptr[n1] = e1;
    if (b == NBUK - 1 && t == 0) rowptr[NNODES] = hi;
    h[t] = e0;           // repurpose as fill cursors
    h[t + 256] = e1;
    __syncthreads();
    for (int i = lo + t; i < hi; i += 256) {
        unsigned en = ebuf[i];
        int pos = atomicAdd(&h[en >> 20], 1);
        int s = (int)(en & 0xFFFFF);
        // INDEX form (wave-uniform) -> scalar-base gathers in k_accum.
        srcidx[pos] = s < NNODES ? s : 0;  // clamp: degrade, never fault
    }
}

// Load one 64-row x tile slice (16 bf16) into registers.
// MODE 0: rows from concat(u,v), dtype per bfflag.
// MODE 1: x = relu(ab*A + ab') with A stored as bf16.
template <int MODE>
__device__ __forceinline__ void stage_load(
    int tile, int tid, int bfflag,
    const void* u, const void* v, const unsigned short* Aacc,
    const float* ab, uint4& w0, uint4& w1)
{
    int r = tid >> 2, c0 = (tid & 3) * 16;
    int row = tile * DD + r;
    int rowc = row < NNODES ? row : NNODES - 1;
    if (MODE == 0) {
        const void* src = (rowc < NUSERS) ? u : v;
        size_t off = (rowc < NUSERS) ? ((size_t)rowc * DD + c0)
                                     : ((size_t)(rowc - NUSERS) * DD + c0);
        if (bfflag) {
            const uint4* p = (const uint4*)((const unsigned short*)src + off);
            w0 = p[0];
            w1 = p[1];
        } else {
            const float4* p = (const float4*)((const float*)src + off);
            float4 f0 = p[0], f1 = p[1], f2 = p[2], f3 = p[3];
            w0 = make_uint4(pack2(f0.x, f0.y), pack2(f0.z, f0.w),
                            pack2(f1.x, f1.y), pack2(f1.z, f1.w));
            w1 = make_uint4(pack2(f2.x, f2.y), pack2(f2.z, f2.w),
                            pack2(f3.x, f3.y), pack2(f3.z, f3.w));
        }
    } else {
        const uint4* p = (const uint4*)(Aacc + (size_t)rowc * DD + c0);
        unsigned aw[8];
        *(uint4*)&aw[0] = p[0];
        *(uint4*)&aw[4] = p[1];
        const float4* pa = (const float4*)(ab + c0);
        const float4* pb = (const float4*)(ab + 64 + c0);
        float av[16], bv[16];
#pragma unroll
        for (int j = 0; j < 4; j++) {
            float4 fa = pa[j], fb = pb[j];
            av[4 * j] = fa.x; av[4 * j + 1] = fa.y;
            av[4 * j + 2] = fa.z; av[4 * j + 3] = fa.w;
            bv[4 * j] = fb.x; bv[4 * j + 1] = fb.y;
            bv[4 * j + 2] = fb.z; bv[4 * j + 3] = fb.w;
        }
        unsigned ow[8];
#pragma unroll
        for (int j = 0; j < 8; j++)
            ow[j] = pr2(lo_bf16(aw[j]), hi_bf16(aw[j]),
                        av[2 * j], av[2 * j + 1], bv[2 * j], bv[2 * j + 1]);
        w0 = *(uint4*)&ow[0];
        w1 = *(uint4*)&ow[4];
    }
}

__device__ __forceinline__ void stage_store(unsigned short* xbuf, int tid,
                                            const uint4& w0, const uint4& w1)
{
    int r = tid >> 2, c0 = (tid & 3) * 16;
    *(uint4*)&xbuf[r * 72 + c0] = w0;
    *((uint4*)&xbuf[r * 72 + c0] + 1) = w1;
}

// ---- MFMA fused 4-GEMM, double-buffered + pipelined. Balanced: 2 tiles/block.
// wave0: A = x@W0 + b0 (bf16)   wave1: Ed = exp(-(x@W1 + b1)) (bf16)
// waves 2/3: T = bits(x@W2) | bits(exp(-(x@W3)))<<16
// Epilogue: DIRECT scattered 2B stores (round-10 revert). The round-5
// LDS-transpose epilogue was based on an artifact WRITE_SIZE reading; the
// cross-round ledger shows it COST ~7-17 µs (L2 write-back coalesces the
// partial-line stores; the LDS round-trip + store-phase serialization were
// pure overhead at this shallow 2-tile pipeline).
// MODE 1 computes BN coefficients in-block from the NSH-way sharded red.
template <int MODE>
__global__ __launch_bounds__(256, 4) void k_mm4_mfma(
    const void* __restrict__ u, const void* __restrict__ v,
    const float* __restrict__ red, const void* __restrict__ gm,
    const void* __restrict__ bt,
    const void* __restrict__ W0, const void* __restrict__ W1,
    const void* __restrict__ W2, const void* __restrict__ W3,
    const void* __restrict__ b0, const void* __restrict__ b1,
    const int* __restrict__ flag,
    unsigned short* __restrict__ A, unsigned short* __restrict__ Ed,
    unsigned* __restrict__ Tw)
{
    __shared__ __align__(16) unsigned short lsd[4 * DD * 72];  // 36,864 B
    __shared__ __align__(16) float abs_s[128];
    const int bfflag = flag[0];
    const int tid = threadIdx.x;

    if (MODE == 1) {
        // fused k_stats over shards: ab = gamma*rstd ; ab' = beta - mean*a
        if (tid < 64) {
            float sm = 0.f, sq = 0.f;
#pragma unroll 8
            for (int s = 0; s < NSH; s++) {
                sm += red[s * 256 + tid];
                sq += red[s * 256 + 128 + tid];
            }
            float mean = sm * (1.f / NNODES);
            float var = sq * (1.f / NNODES) - mean * mean;
            float a = ldf(gm, tid, bfflag) * rsqrtf(var + 1e-3f);
            abs_s[tid] = a;
            abs_s[64 + tid] = ldf(bt, tid, bfflag) - mean * a;
        }
        __syncthreads();
    }

    // Issue first x-tile load ASAP (hidden behind weight staging).
    int t = blockIdx.x;
    uint4 xa, xb;
    stage_load<MODE>(t, tid, bfflag, u, v, A, abs_s, xa, xb);

    if (bfflag) {
#define WSTG_BF(m, src)                                                   \
        _Pragma("unroll")                                                 \
        for (int j = 0; j < 2; j++) {                                     \
            int i = tid + j * 256; int e0 = i * 8;                        \
            *(uint4*)&lsd[(m) * 4608 + (e0 >> 6) * 72 + (e0 & 63)] =      \
                ((const uint4*)(src))[i];                                 \
        }
        WSTG_BF(0, W0) WSTG_BF(1, W1) WSTG_BF(2, W2) WSTG_BF(3, W3)
    } else {
#define WSTG_F32(m, src)                                                  \
        _Pragma("unroll")                                                 \
        for (int j = 0; j < 4; j++) {                                     \
            int i = tid + j * 256; int e0 = i * 4;                        \
            float4 f = ((const float4*)(src))[i];                         \
            *(uint2*)&lsd[(m) * 4608 + (e0 >> 6) * 72 + (e0 & 63)] =      \
                make_uint2(pack2(f.x, f.y), pack2(f.z, f.w));             \
        }
        WSTG_F32(0, W0) WSTG_F32(1, W1) WSTG_F32(2, W2) WSTG_F32(3, W3)
    }
    __syncthreads();

    const int wv = tid >> 6, lane = tid & 63;
    const int quad = lane >> 4, ln = lane & 15;
    const int mA = (wv < 2) ? wv : 2;
    bf16x8 bfrA[2][4], bfrB[2][4];
#pragma unroll
    for (int ks = 0; ks < 2; ks++)
#pragma unroll
        for (int nt = 0; nt < 4; nt++)
#pragma unroll
            for (int j = 0; j < 8; j++)
                bfrA[ks][nt][j] = (short)lsd[mA * 4608 +
                    (ks * 32 + quad * 8 + j) * 72 + nt * 16 + ln];
    if (wv >= 2) {
#pragma unroll
        for (int ks = 0; ks < 2; ks++)
#pragma unroll
            for (int nt = 0; nt < 4; nt++)
#pragma unroll
                for (int j = 0; j < 8; j++)
                    bfrB[ks][nt][j] = (short)lsd[3 * 4608 +
                        (ks * 32 + quad * 8 + j) * 72 + nt * 16 + ln];
    }
    float bias[4];
#pragma unroll
    for (int nt = 0; nt < 4; nt++)
        bias[nt] = (wv == 0) ? ldf(b0, nt * 16 + ln, bfflag)
                 : (wv == 1) ? ldf(b1, nt * 16 + ln, bfflag) : 0.f;
    __syncthreads();  // weights fully consumed; regions 0/1 become x buffers

    auto compute = [&](const unsigned short* xt, int row0) {
        if (wv < 2) {
#pragma unroll
            for (int rt = 0; rt < 4; rt++) {
                int m = rt * 16 + ln;
                bf16x8 af0 = *(const bf16x8*)&xt[m * 72 + quad * 8];
                bf16x8 af1 = *(const bf16x8*)&xt[m * 72 + 32 + quad * 8];
#pragma unroll
                for (int nt = 0; nt < 4; nt++) {
                    f32x4 c = {0.f, 0.f, 0.f, 0.f};
                    c = __builtin_amdgcn_mfma_f32_16x16x32_bf16(af0, bfrA[0][nt], c, 0, 0, 0);
                    c = __builtin_amdgcn_mfma_f32_16x16x32_bf16(af1, bfrA[1][nt], c, 0, 0, 0);
                    int col = nt * 16 + ln;
#pragma unroll
                    for (int r = 0; r < 4; r++) {
                        int row = row0 + rt * 16 + quad * 4 + r;
                        if (row < NNODES) {
                            size_t o = (size_t)row * DD + col;
                            if (wv == 0) A[o] = fbits(c[r] + bias[nt]);
                            else         Ed[o] = fbits(__expf(-(c[r] + bias[nt])));
                        }
                    }
                }
            }
        } else {
            const int rtb = (wv - 2) * 2;
#pragma unroll
            for (int rr = 0; rr < 2; rr++) {
                int rt = rtb + rr;
                int m = rt * 16 + ln;
                bf16x8 af0 = *(const bf16x8*)&xt[m * 72 + quad * 8];
                bf16x8 af1 = *(const bf16x8*)&xt[m * 72 + 32 + quad * 8];
#pragma unroll
                for (int nt = 0; nt < 4; nt++) {
                    f32x4 c2 = {0.f, 0.f, 0.f, 0.f};
                    f32x4 c3 = {0.f, 0.f, 0.f, 0.f};
                    c2 = __builtin_amdgcn_mfma_f32_16x16x32_bf16(af0, bfrA[0][nt], c2, 0, 0, 0);
                    c2 = __builtin_amdgcn_mfma_f32_16x16x32_bf16(af1, bfrA[1][nt], c2, 0, 0, 0);
                    c3 = __builtin_amdgcn_mfma_f32_16x16x32_bf16(af0, bfrB[0][nt], c3, 0, 0, 0);
                    c3 = __builtin_amdgcn_mfma_f32_16x16x32_bf16(af1, bfrB[1][nt], c3, 0, 0, 0);
                    int col = nt * 16 + ln;
#pragma unroll
                    for (int r = 0; r < 4; r++) {
                        int row = row0 + rt * 16 + quad * 4 + r;
                        if (row < NNODES)
                            Tw[(size_t)row * DD + col] =
                                pack2(c2[r], __expf(-c3[r]));
                    }
                }
            }
        }
    };

    // Pipelined tile loop (double-buffered x in the reclaimed weight LDS).
    stage_store(lsd, tid, xa, xb);
    int tn = t + GMM;
    if (tn < NGB)
        stage_load<MODE>(tn, tid, bfflag, u, v, A, abs_s, xa, xb);
    __syncthreads();
    int buf = 0;
    while (true) {
        compute(lsd + buf * 4608, t * DD);
        if (tn >= NGB) break;
        t = tn;
        tn += GMM;
        stage_store(lsd + (buf ^ 1) * 4608, tid, xa, xb);
        if (tn < NGB)
            stage_load<MODE>(tn, tid, bfflag, u, v, A, abs_s, xa, xb);
        __syncthreads();
        buf ^= 1;
    }
}

// ---- MFMA final: out = relu(ab*A + ab' + x_in@R); wave w = rowtile w.
// ab computed in-block from SHARDED red2 counters (fused k_stats).
// Direct stores (round-10 revert — LDS output staging cost time, see mm4).
__global__ __launch_bounds__(256) void k_final_mfma(
    const unsigned short* __restrict__ A, const float* __restrict__ red,
    const void* __restrict__ gm, const void* __restrict__ bt,
    const void* __restrict__ u, const void* __restrict__ v,
    const void* __restrict__ R, const int* __restrict__ flag,
    void* __restrict__ out)
{
    __shared__ __align__(16) unsigned short Wls[DD][72];
    __shared__ __align__(16) unsigned short xls[DD][72];
    __shared__ __align__(16) float abf[128];
    const int bfflag = flag[0];
    const int tid = threadIdx.x;
    if (tid < 64) {
        float sm = 0.f, sq = 0.f;
#pragma unroll 8
        for (int s = 0; s < NSH; s++) {
            sm += red[s * 256 + tid];
            sq += red[s * 256 + 128 + tid];
        }
        float mean = sm * (1.f / NNODES);
        float var = sq * (1.f / NNODES) - mean * mean;
        float a = ldf(gm, tid, bfflag) * rsqrtf(var + 1e-3f);
        abf[tid] = a;
        abf[64 + tid] = ldf(bt, tid, bfflag) - mean * a;
    }
    if (bfflag) {
        for (int i = tid; i < 512; i += 256) {
            int e0 = i * 8;
            *(uint4*)&Wls[e0 >> 6][e0 & 63] = ((const uint4*)R)[i];
        }
    } else {
        for (int i = tid; i < 1024; i += 256) {
            int e0 = i * 4;
            float4 f = ((const float4*)R)[i];
            *(uint2*)&Wls[e0 >> 6][e0 & 63] =
                make_uint2(pack2(f.x, f.y), pack2(f.z, f.w));
        }
    }
    uint4 w0, w1;
    stage_load<0>(blockIdx.x, tid, bfflag, u, v, nullptr, nullptr, w0, w1);
    stage_store(&xls[0][0], tid, w0, w1);
    __syncthreads();

    const int row0 = blockIdx.x * DD;
    const int wv = tid >> 6, lane = tid & 63;
    const int quad = lane >> 4, ln = lane & 15;
    bf16x8 bfr[2][4];
#pragma unroll
    for (int ks = 0; ks < 2; ks++)
#pragma unroll
        for (int nt = 0; nt < 4; nt++)
#pragma unroll
            for (int j = 0; j < 8; j++)
                bfr[ks][nt][j] = (short)Wls[ks * 32 + quad * 8 + j][nt * 16 + ln];
    float av[4], bv[4];
#pragma unroll
    for (int nt = 0; nt < 4; nt++) {
        av[nt] = abf[nt * 16 + ln];
        bv[nt] = abf[64 + nt * 16 + ln];
    }
    const int rt = wv;
    int m = rt * 16 + ln;
    bf16x8 af0 = *(const bf16x8*)&xls[m][quad * 8];
    bf16x8 af1 = *(const bf16x8*)&xls[m][32 + quad * 8];
#pragma unroll
    for (int nt = 0; nt < 4; nt++) {
        f32x4 c = {0.f, 0.f, 0.f, 0.f};
        c = __builtin_amdgcn_mfma_f32_16x16x32_bf16(af0, bfr[0][nt], c, 0, 0, 0);
        c = __builtin_amdgcn_mfma_f32_16x16x32_bf16(af1, bfr[1][nt], c, 0, 0, 0);
        int col = nt * 16 + ln;
#pragma unroll
        for (int r = 0; r < 4; r++) {
            int row = row0 + rt * 16 + quad * 4 + r;
            if (row < NNODES) {
                size_t o = (size_t)row * DD + col;
                float vv = av[nt] * us2f(A[o]) + bv[nt] + c[r];
                vv = vv > 0.f ? vv : 0.f;
                if (bfflag) ((unsigned short*)out)[o] = fbits(vv);
                else        ((float*)out)[o] = vv;
            }
        }
    }
}

// ---- Gather-accumulate: 4 nodes per wave, pair-interleaved gathers +
// fused column sum/sumsq reduction with NSH-way sharded atomics.
// At its structural floor (~50 µs): two MLP-deepening probes (r7 header
// batch, r9 pair-interleave) were null -> bound by L3/fabric random-256B
// service rate on the 256 MB logical gather (124.6 MB L2-miss @ ~2.5 TB/s).
// srcidx wave-uniform -> s_load + scalar-base gathers (round-1 lesson).
__global__ __launch_bounds__(256) void k_accum(
    const int* __restrict__ rowptr, const int* __restrict__ srcidx,
    const unsigned* __restrict__ T, const bf16* __restrict__ Ed,
    unsigned short* __restrict__ A, float* __restrict__ red)
{
    __shared__ float s1[256], s2[256];
    const int wv = threadIdx.x >> 6, c = threadIdx.x & 63;
    const int d0 = blockIdx.x * 16 + wv * 4;  // grid 6250 -> d0 in [0,100000)
    int rp0 = rowptr[d0], rp1 = rowptr[d0 + 1], rp2 = rowptr[d0 + 2],
        rp3 = rowptr[d0 + 3], rp4 = rowptr[d0 + 4];
    size_t o0 = (size_t)d0 * DD + c;
    float edA = b2f(Ed[o0]),       edB = b2f(Ed[o0 + 64]),
          edC = b2f(Ed[o0 + 128]), edD = b2f(Ed[o0 + 192]);
    float sA = us2f(A[o0]),       sB = us2f(A[o0 + 64]),
          sC = us2f(A[o0 + 128]), sD = us2f(A[o0 + 192]);

#define EDGE(sv, edv, tv) sv += lo_bf16(tv) * \
    __builtin_amdgcn_rcpf(1.f + edv * hi_bf16(tv));
#define NODE_TAIL(sv, edv, i, r1)                                   \
    {                                                               \
        for (; i + 3 < r1; i += 4) {                                \
            unsigned t0 = T[(size_t)srcidx[i] * DD + c];            \
            unsigned t1 = T[(size_t)srcidx[i + 1] * DD + c];        \
            unsigned t2 = T[(size_t)srcidx[i + 2] * DD + c];        \
            unsigned t3 = T[(size_t)srcidx[i + 3] * DD + c];        \
            EDGE(sv, edv, t0) EDGE(sv, edv, t1)                     \
            EDGE(sv, edv, t2) EDGE(sv, edv, t3)                     \
        }                                                           \
        for (; i < r1; i++) {                                       \
            unsigned t0 = T[(size_t)srcidx[i] * DD + c];            \
            EDGE(sv, edv, t0)                                       \
        }                                                           \
    }
#define PAIR_LOOP(sX, edX, x0, x1, sY, edY, y0, y1)                 \
    {                                                               \
        int iX = x0, iY = y0;                                       \
        while (iX + 3 < x1 && iY + 3 < y1) {                        \
            unsigned a0 = T[(size_t)srcidx[iX] * DD + c];           \
            unsigned a1 = T[(size_t)srcidx[iX + 1] * DD + c];       \
            unsigned a2 = T[(size_t)srcidx[iX + 2] * DD + c];       \
            unsigned a3 = T[(size_t)srcidx[iX + 3] * DD + c];       \
            unsigned b0 = T[(size_t)srcidx[iY] * DD + c];           \
            unsigned b1 = T[(size_t)srcidx[iY + 1] * DD + c];       \
            unsigned b2 = T[(size_t)srcidx[iY + 2] * DD + c];       \
            unsigned b3 = T[(size_t)srcidx[iY + 3] * DD + c];       \
            EDGE(sX, edX, a0) EDGE(sX, edX, a1)                     \
            EDGE(sX, edX, a2) EDGE(sX, edX, a3)                     \
            EDGE(sY, edY, b0) EDGE(sY, edY, b1)                     \
            EDGE(sY, edY, b2) EDGE(sY, edY, b3)                     \
            iX += 4; iY += 4;                                       \
        }                                                           \
        NODE_TAIL(sX, edX, iX, x1)                                  \
        NODE_TAIL(sY, edY, iY, y1)                                  \
    }

    PAIR_LOOP(sA, edA, rp0, rp1, sB, edB, rp1, rp2)
    A[o0] = fbits(sA);
    A[o0 + 64] = fbits(sB);
    PAIR_LOOP(sC, edC, rp2, rp3, sD, edD, rp3, rp4)
    A[o0 + 128] = fbits(sC);
    A[o0 + 192] = fbits(sD);
#undef PAIR_LOOP
#undef NODE_TAIL
#undef EDGE

    // fused k_reduce: block partial -> one sharded atomic per counter.
    s1[threadIdx.x] = (sA + sB) + (sC + sD);
    s2[threadIdx.x] = (sA * sA + sB * sB) + (sC * sC + sD * sD);
    __syncthreads();
    if (threadIdx.x < 64) {
        float a = s1[c] + s1[64 + c] + s1[128 + c] + s1[192 + c];
        float b = s2[c] + s2[64 + c] + s2[128 + c] + s2[192 + c];
        float* sh = red + (blockIdx.x & (NSH - 1)) * 256;
        unsafeAtomicAdd(&sh[c], a);
        unsafeAtomicAdd(&sh[128 + c], b);
    }
}

extern "C" void kernel_launch(void* const* d_in, const int* in_sizes, int n_in,
                              void* d_out, int out_size, void* d_ws, size_t ws_size,
                              hipStream_t stream)
{
    const void* u   = d_in[0];
    const void* v   = d_in[1];
    const int* es   = (const int*)d_in[2];
    const int* ee   = (const int*)d_in[3];
    const void* Ui1 = d_in[4];
    const void* Uj1 = d_in[5];
    const void* Vi1 = d_in[6];
    const void* Vj1 = d_in[7];
    const void* bu1 = d_in[8];
    const void* bv1 = d_in[9];
    const void* Ui2 = d_in[10];
    const void* Uj2 = d_in[11];
    const void* Vi2 = d_in[12];
    const void* Vj2 = d_in[13];
    const void* bu2 = d_in[14];
    const void* bv2 = d_in[15];
    const void* R   = d_in[16];
    const void* g1  = d_in[17];
    const void* be1 = d_in[18];
    const void* g2  = d_in[19];
    const void* be2 = d_in[20];
    const int E = in_sizes[2];

    // Workspace (~56.8 MB; proven round-7 layout).
    // ebuf aliases T (CSR build fully precedes k_mm4<0>'s T writes).
    // bh (400 KB) aliases srcidx (bh dead before k_group writes srcidx).
    // Ed lives in d_out until k_final overwrites it.
    // Sharded red counters (2 x 64 KB) in the srcidx..rowptr hole.
    char* ws = (char*)d_ws;
    unsigned short* A = (unsigned short*)(ws);      // 12.8 MB bf16 accumulator
    unsigned* T    = (unsigned*)(ws + 25600000);    // 25.6 MB (Ui | exp(-Vj)<<16)
    unsigned* ebuf = (unsigned*)(ws + 25600000);    // 4 MB, aliases T
    int* srcidx    = (int*)(ws + 51200000);         // 4 MB (ends 55,200,000)
    int* bh        = (int*)(ws + 51200000);         // 400 KB, aliases srcidx
    float* redsh   = (float*)(ws + 55200000);       // 128 KB sharded counters
    int* rowptr    = (int*)(ws + 56000000);         // 400,004 B
    int* flag      = (int*)(ws + 56804224);
    int* bbase     = (int*)(ws + 56805376);         // 256 ints (ends 56806400)
    int* bcursor   = (int*)(ws + 56806400);         // 256 ints
    float* red1 = redsh;                  // NSH shards x 256 floats
    float* red2 = redsh + NSH * 256;      // NSH shards x 256 floats
    bf16* Ed = (bf16*)d_out;

    // ---- CSR build (round-7 proven) ----
    k_bhist<<<NBH, 256, 0, stream>>>(ee, (const unsigned short*)u, flag, bh, E);
    k_bscan<<<1, 1024, 0, stream>>>(bh, bbase, bcursor, redsh);
    k_bscatter<<<(E + ESB - 1) / ESB, 256, 0, stream>>>(es, ee, bcursor, ebuf, E);
    k_group<<<NBUK, 256, 0, stream>>>(bbase, ebuf, rowptr, srcidx);

    // ---- stage 1 ----
    k_mm4_mfma<0><<<GMM, 256, 0, stream>>>(u, v, nullptr, nullptr, nullptr,
                                           Uj1, Vi1, Ui1, Vj1, bu1, bv1, flag,
                                           A, (unsigned short*)Ed, T);
    k_accum<<<NNODES / 16, 256, 0, stream>>>(rowptr, srcidx, T, Ed, A, red1);

    // ---- stage 2 (BN1+relu fused into staging; stats fused into k_mm4) ----
    k_mm4_mfma<1><<<GMM, 256, 0, stream>>>(nullptr, nullptr, red1, g1, be1,
                                           Uj2, Vi2, Ui2, Vj2, bu2, bv2, flag,
                                           A, (unsigned short*)Ed, T);
    k_accum<<<NNODES / 16, 256, 0, stream>>>(rowptr, srcidx, T, Ed, A, red2);

    // ---- BN2 + residual (x_in@R via MFMA) + relu -> out ----
    k_final_mfma<<<NGB, 256, 0, stream>>>(A, red2, g2, be2, u, v, R, flag, d_out);
}

// Round 11
// 334.297 us; speedup vs baseline: 1.0176x; 1.0176x over previous
//
#include <hip/hip_runtime.h>
#include <hip/hip_bf16.h>

#define NUSERS 60000
#define NNODES 100000
#define DD 64
#define NGB 1563  // ceil(NNODES/64) — 64-row tiles
#define GMM 782   // k_mm4 grid: exactly 2 tiles per block (balanced)
#define NBUK 196  // ceil(NNODES/512) coarse buckets (dst>>9)
#define ESB 2048  // edges per k_bscatter block
#define NBH 400   // k_bhist blocks (partial-hist rows)
#define NSH 64    // reduction shards (6250 blocks / 64 ≈ 98 adds/address)

typedef __hip_bfloat16 bf16;
using bf16x8 = __attribute__((ext_vector_type(8))) short;
using f32x4  = __attribute__((ext_vector_type(4))) float;

__device__ __forceinline__ float b2f(bf16 x) { return __bfloat162float(x); }
__device__ __forceinline__ bf16 f2b(float x) { return __float2bfloat16(x); }
// NOTE (round-6 lesson): do NOT replace with v_cvt_pk_bf16_f32 inline asm.
// Produced absmax=237 (scrambled T halves). __float2bfloat16 is the
// proven-correct path.
__device__ __forceinline__ unsigned short fbits(float x) {
    union { bf16 b; unsigned short u; } cv; cv.b = f2b(x); return cv.u;
}
__device__ __forceinline__ float us2f(unsigned short h) {
    union { unsigned u; float f; } t; t.u = (unsigned)h << 16; return t.f;
}
__device__ __forceinline__ float lo_bf16(unsigned w) {
    union { unsigned u; float f; } t; t.u = w << 16; return t.f;
}
__device__ __forceinline__ float hi_bf16(unsigned w) {
    union { unsigned u; float f; } t; t.u = w & 0xFFFF0000u; return t.f;
}
__device__ __forceinline__ float ldf(const void* p, size_t i, int isbf) {
    if (isbf) return b2f(((const bf16*)p)[i]);
    return ((const float*)p)[i];
}
__device__ __forceinline__ unsigned pack2(float a, float b) {
    return (unsigned)fbits(a) | ((unsigned)fbits(b) << 16);
}
__device__ __forceinline__ unsigned pr2(float x0, float x1, float a0, float a1,
                                        float b0, float b1) {
    float t0 = a0 * x0 + b0, t1 = a1 * x1 + b1;
    t0 = t0 > 0.f ? t0 : 0.f;
    t1 = t1 > 0.f ? t1 : 0.f;
    return pack2(t0, t1);
}

// ---- CSR build step 1 (+ fused dtype sniff in block 0). Round-7 proven.
__global__ __launch_bounds__(256) void k_bhist(
    const int* __restrict__ ee, const unsigned short* __restrict__ hsn,
    int* __restrict__ flag, int* __restrict__ bh, int E)
{
    __shared__ int h[256];
    int t = threadIdx.x;
    if (blockIdx.x == 0) {
        int cnt = 0;
        for (int i = t; i < 1024; i += 256) {
            int e = (hsn[2 * i] >> 7) & 0xFF;
            cnt += (e >= 100 && e <= 140) ? 1 : 0;
        }
        h[t] = cnt;
        __syncthreads();
        for (int s = 128; s > 0; s >>= 1) {
            if (t < s) h[t] += h[t + s];
            __syncthreads();
        }
        if (t == 0) flag[0] = (h[0] > 512) ? 1 : 0;
        __syncthreads();
    }
    h[t] = 0;
    __syncthreads();
    for (int e = blockIdx.x * 256 + t; e < E; e += gridDim.x * 256)
        atomicAdd(&h[ee[e] >> 9], 1);
    __syncthreads();
    bh[blockIdx.x * 256 + t] = h[t];
}

// Sum partial hists (4-way row-parallel, 1024 threads) -> scan ->
// bbase/bcursor. Also zeroes the sharded reduction counters.
// NOTE: no bbase[256] write — would alias bcursor[0].
__global__ __launch_bounds__(1024) void k_bscan(
    const int* __restrict__ bh, int* __restrict__ bbase,
    int* __restrict__ bcursor, float* __restrict__ redz)
{
    __shared__ int ps[1024];
    __shared__ int sd[256];
    int t = threadIdx.x;
    int col = t & 255, seg = t >> 8;       // 4 segments x 100 rows
    int v = 0;
#pragma unroll 4
    for (int b = seg * 100; b < (seg + 1) * 100; b++)
        v += bh[b * 256 + col];
    ps[t] = v;
    __syncthreads();
    int vv = 0;
    if (t < 256) {
        vv = ps[t] + ps[t + 256] + ps[t + 512] + ps[t + 768];
        sd[t] = vv;
    }
    __syncthreads();
    for (int off = 1; off < 256; off <<= 1) {
        int x = (t >= off && t < 256) ? sd[t - off] : 0;
        __syncthreads();
        if (t < 256) sd[t] += x;
        __syncthreads();
    }
    if (t < 256) {
        int excl = sd[t] - vv;
        bbase[t] = excl;
        bcursor[t] = excl;
    }
    for (int i = t; i < 2 * NSH * 256; i += 1024) redz[i] = 0.f;
}

// Entry = (dst&511)<<20 | src  (src < 2^17). Atomic bcursor allocation
// (round-7 proven): order within bucket is irrelevant — k_group re-orders
// per-node via its own cursors.
__global__ __launch_bounds__(256) void k_bscatter(
    const int* __restrict__ es, const int* __restrict__ ee,
    int* __restrict__ bcursor, unsigned* __restrict__ ebuf, int E)
{
    __shared__ int h[256], gb[256], lr[256];
    int t = threadIdx.x;
    h[t] = 0;
    lr[t] = 0;
    __syncthreads();
    int base = blockIdx.x * ESB;
    unsigned ent[8];
    int bk[8];
#pragma unroll
    for (int i = 0; i < 8; i++) {
        int e = base + t + i * 256;
        if (e < E) {
            int s = es[e], d = ee[e];
            bk[i] = d >> 9;
            ent[i] = (unsigned)s | ((unsigned)(d & 511) << 20);
            atomicAdd(&h[bk[i]], 1);
        } else bk[i] = -1;
    }
    __syncthreads();
    if (h[t]) gb[t] = atomicAdd(&bcursor[t], h[t]);
    __syncthreads();
#pragma unroll
    for (int i = 0; i < 8; i++) {
        if (bk[i] >= 0) {
            int r = atomicAdd(&lr[bk[i]], 1);
            ebuf[gb[bk[i]] + r] = ent[i];
        }
    }
}

__global__ __launch_bounds__(256) void k_group(
    const int* __restrict__ bbase, const unsigned* __restrict__ ebuf,
    int* __restrict__ rowptr, int* __restrict__ srcidx)
{
    __shared__ int h[512], sc[512];
    int b = blockIdx.x, t = threadIdx.x;
    int lo = bbase[b], hi = bbase[b + 1];
    h[t] = 0;
    h[t + 256] = 0;
    __syncthreads();
    for (int i = lo + t; i < hi; i += 256)
        atomicAdd(&h[ebuf[i] >> 20], 1);
    __syncthreads();
    sc[t] = h[t];
    sc[t + 256] = h[t + 256];
    __syncthreads();
    for (int off = 1; off < 512; off <<= 1) {
        int v0 = (t >= off) ? sc[t - off] : 0;
        int v1 = (t + 256 >= off) ? sc[t + 256 - off] : 0;
        __syncthreads();
        sc[t] += v0;
        sc[t + 256] += v1;
        __syncthreads();
    }
    int n0 = b * 512 + t, n1 = b * 512 + t + 256;
    int e0 = lo + sc[t] - h[t];
    int e1 = lo + sc[t + 256] - h[t + 256];
    if (n0 < NNODES) rowptr[n0] = e0;
    if (n1 < NNODES) rowptr[n1] = e1;
    if (b == NBUK - 1 && t == 0) rowptr[NNODES] = hi;
    h[t] = e0;           // repurpose as fill cursors
    h[t + 256] = e1;
    __syncthreads();
    for (int i = lo + t; i < hi; i += 256) {
        unsigned en = ebuf[i];
        int pos = atomicAdd(&h[en >> 20], 1);
        int s = (int)(en & 0xFFFFF);
        // INDEX form (wave-uniform) -> scalar-base gathers in k_accum.
        srcidx[pos] = s < NNODES ? s : 0;  // clamp: degrade, never fault
    }
}

// Load one 64-row x tile slice (16 bf16) into registers.
// MODE 0: rows from concat(u,v), dtype per bfflag.
// MODE 1: x = relu(ab*A + ab') with A stored as bf16.
template <int MODE>
__device__ __forceinline__ void stage_load(
    int tile, int tid, int bfflag,
    const void* u, const void* v, const unsigned short* Aacc,
    const float* ab, uint4& w0, uint4& w1)
{
    int r = tid >> 2, c0 = (tid & 3) * 16;
    int row = tile * DD + r;
    int rowc = row < NNODES ? row : NNODES - 1;
    if (MODE == 0) {
        const void* src = (rowc < NUSERS) ? u : v;
        size_t off = (rowc < NUSERS) ? ((size_t)rowc * DD + c0)
                                     : ((size_t)(rowc - NUSERS) * DD + c0);
        if (bfflag) {
            const uint4* p = (const uint4*)((const unsigned short*)src + off);
            w0 = p[0];
            w1 = p[1];
        } else {
            const float4* p = (const float4*)((const float*)src + off);
            float4 f0 = p[0], f1 = p[1], f2 = p[2], f3 = p[3];
            w0 = make_uint4(pack2(f0.x, f0.y), pack2(f0.z, f0.w),
                            pack2(f1.x, f1.y), pack2(f1.z, f1.w));
            w1 = make_uint4(pack2(f2.x, f2.y), pack2(f2.z, f2.w),
                            pack2(f3.x, f3.y), pack2(f3.z, f3.w));
        }
    } else {
        const uint4* p = (const uint4*)(Aacc + (size_t)rowc * DD + c0);
        unsigned aw[8];
        *(uint4*)&aw[0] = p[0];
        *(uint4*)&aw[4] = p[1];
        const float4* pa = (const float4*)(ab + c0);
        const float4* pb = (const float4*)(ab + 64 + c0);
        float av[16], bv[16];
#pragma unroll
        for (int j = 0; j < 4; j++) {
            float4 fa = pa[j], fb = pb[j];
            av[4 * j] = fa.x; av[4 * j + 1] = fa.y;
            av[4 * j + 2] = fa.z; av[4 * j + 3] = fa.w;
            bv[4 * j] = fb.x; bv[4 * j + 1] = fb.y;
            bv[4 * j + 2] = fb.z; bv[4 * j + 3] = fb.w;
        }
        unsigned ow[8];
#pragma unroll
        for (int j = 0; j < 8; j++)
            ow[j] = pr2(lo_bf16(aw[j]), hi_bf16(aw[j]),
                        av[2 * j], av[2 * j + 1], bv[2 * j], bv[2 * j + 1]);
        w0 = *(uint4*)&ow[0];
        w1 = *(uint4*)&ow[4];
    }
}

__device__ __forceinline__ void stage_store(unsigned short* xbuf, int tid,
                                            const uint4& w0, const uint4& w1)
{
    int r = tid >> 2, c0 = (tid & 3) * 16;
    *(uint4*)&xbuf[r * 72 + c0] = w0;
    *((uint4*)&xbuf[r * 72 + c0] + 1) = w1;
}

// ---- MFMA fused 4-GEMM, double-buffered + pipelined. Balanced: 2 tiles/block.
// wave0: A = x@W0 + b0 (bf16)   wave1: Ed = exp(-(x@W1 + b1)) (bf16)
// waves 2/3: T = bits(x@W2) | bits(exp(-(x@W3)))<<16
// A/Ed epilogue is LDS-transposed, writing full 128-B rows (round-10 A/B:
// direct scattered 2B stores were +4 µs total — keep the staged version).
// MODE 1 computes BN coefficients in-block from the NSH-way sharded red.
template <int MODE>
__global__ __launch_bounds__(256, 4) void k_mm4_mfma(
    const void* __restrict__ u, const void* __restrict__ v,
    const float* __restrict__ red, const void* __restrict__ gm,
    const void* __restrict__ bt,
    const void* __restrict__ W0, const void* __restrict__ W1,
    const void* __restrict__ W2, const void* __restrict__ W3,
    const void* __restrict__ b0, const void* __restrict__ b1,
    const int* __restrict__ flag,
    unsigned short* __restrict__ A, unsigned short* __restrict__ Ed,
    unsigned* __restrict__ Tw)
{
    __shared__ __align__(16) unsigned short lsd[4 * DD * 72];  // 36,864 B
    __shared__ __align__(16) float abs_s[128];
    const int bfflag = flag[0];
    const int tid = threadIdx.x;

    if (MODE == 1) {
        // fused k_stats over shards: ab = gamma*rstd ; ab' = beta - mean*a
        if (tid < 64) {
            float sm = 0.f, sq = 0.f;
#pragma unroll 8
            for (int s = 0; s < NSH; s++) {
                sm += red[s * 256 + tid];
                sq += red[s * 256 + 128 + tid];
            }
            float mean = sm * (1.f / NNODES);
            float var = sq * (1.f / NNODES) - mean * mean;
            float a = ldf(gm, tid, bfflag) * rsqrtf(var + 1e-3f);
            abs_s[tid] = a;
            abs_s[64 + tid] = ldf(bt, tid, bfflag) - mean * a;
        }
        __syncthreads();
    }

    // Issue first x-tile load ASAP (hidden behind weight staging).
    int t = blockIdx.x;
    uint4 xa, xb;
    stage_load<MODE>(t, tid, bfflag, u, v, A, abs_s, xa, xb);

    if (bfflag) {
#define WSTG_BF(m, src)                                                   \
        _Pragma("unroll")                                                 \
        for (int j = 0; j < 2; j++) {                                     \
            int i = tid + j * 256; int e0 = i * 8;                        \
            *(uint4*)&lsd[(m) * 4608 + (e0 >> 6) * 72 + (e0 & 63)] =      \
                ((const uint4*)(src))[i];                                 \
        }
        WSTG_BF(0, W0) WSTG_BF(1, W1) WSTG_BF(2, W2) WSTG_BF(3, W3)
    } else {
#define WSTG_F32(m, src)                                                  \
        _Pragma("unroll")                                                 \
        for (int j = 0; j < 4; j++) {                                     \
            int i = tid + j * 256; int e0 = i * 4;                        \
            float4 f = ((const float4*)(src))[i];                         \
            *(uint2*)&lsd[(m) * 4608 + (e0 >> 6) * 72 + (e0 & 63)] =      \
                make_uint2(pack2(f.x, f.y), pack2(f.z, f.w));             \
        }
        WSTG_F32(0, W0) WSTG_F32(1, W1) WSTG_F32(2, W2) WSTG_F32(3, W3)
    }
    __syncthreads();

    const int wv = tid >> 6, lane = tid & 63;
    const int quad = lane >> 4, ln = lane & 15;
    const int mA = (wv < 2) ? wv : 2;
    bf16x8 bfrA[2][4], bfrB[2][4];
#pragma unroll
    for (int ks = 0; ks < 2; ks++)
#pragma unroll
        for (int nt = 0; nt < 4; nt++)
#pragma unroll
            for (int j = 0; j < 8; j++)
                bfrA[ks][nt][j] = (short)lsd[mA * 4608 +
                    (ks * 32 + quad * 8 + j) * 72 + nt * 16 + ln];
    if (wv >= 2) {
#pragma unroll
        for (int ks = 0; ks < 2; ks++)
#pragma unroll
            for (int nt = 0; nt < 4; nt++)
#pragma unroll
                for (int j = 0; j < 8; j++)
                    bfrB[ks][nt][j] = (short)lsd[3 * 4608 +
                        (ks * 32 + quad * 8 + j) * 72 + nt * 16 + ln];
    }
    float bias[4];
#pragma unroll
    for (int nt = 0; nt < 4; nt++)
        bias[nt] = (wv == 0) ? ldf(b0, nt * 16 + ln, bfflag)
                 : (wv == 1) ? ldf(b1, nt * 16 + ln, bfflag) : 0.f;
    __syncthreads();  // weights fully consumed; regions 0/1 become x buffers,
                      // regions 2/3 become wave-0/1 epilogue staging.

    auto compute = [&](const unsigned short* xt, int row0) {
        if (wv < 2) {
            unsigned short* stg = lsd + (2 + wv) * 4608;  // wave-private
#pragma unroll
            for (int rt = 0; rt < 4; rt++) {
                int m = rt * 16 + ln;
                bf16x8 af0 = *(const bf16x8*)&xt[m * 72 + quad * 8];
                bf16x8 af1 = *(const bf16x8*)&xt[m * 72 + 32 + quad * 8];
#pragma unroll
                for (int nt = 0; nt < 4; nt++) {
                    f32x4 c = {0.f, 0.f, 0.f, 0.f};
                    c = __builtin_amdgcn_mfma_f32_16x16x32_bf16(af0, bfrA[0][nt], c, 0, 0, 0);
                    c = __builtin_amdgcn_mfma_f32_16x16x32_bf16(af1, bfrA[1][nt], c, 0, 0, 0);
#pragma unroll
                    for (int r = 0; r < 4; r++) {
                        int lr = rt * 16 + quad * 4 + r;
                        float vv = c[r] + bias[nt];
                        stg[lr * 72 + nt * 16 + ln] =
                            (wv == 0) ? fbits(vv) : fbits(__expf(-vv));
                    }
                }
            }
            // Full-line writeback: 8 passes x (8 rows x 128 B).
            unsigned short* dst = (wv == 0) ? A : Ed;
            int r8 = lane >> 3, c8 = lane & 7;
#pragma unroll
            for (int p = 0; p < 8; p++) {
                int lr = p * 8 + r8;
                uint4 vv = *(const uint4*)&stg[lr * 72 + c8 * 8];
                int row = row0 + lr;
                if (row < NNODES)
                    *(uint4*)&dst[(size_t)row * DD + c8 * 8] = vv;
            }
        } else {
            const int rtb = (wv - 2) * 2;
#pragma unroll
            for (int rr = 0; rr < 2; rr++) {
                int rt = rtb + rr;
                int m = rt * 16 + ln;
                bf16x8 af0 = *(const bf16x8*)&xt[m * 72 + quad * 8];
                bf16x8 af1 = *(const bf16x8*)&xt[m * 72 + 32 + quad * 8];
#pragma unroll
                for (int nt = 0; nt < 4; nt++) {
                    f32x4 c2 = {0.f, 0.f, 0.f, 0.f};
                    f32x4 c3 = {0.f, 0.f, 0.f, 0.f};
                    c2 = __builtin_amdgcn_mfma_f32_16x16x32_bf16(af0, bfrA[0][nt], c2, 0, 0, 0);
                    c2 = __builtin_amdgcn_mfma_f32_16x16x32_bf16(af1, bfrA[1][nt], c2, 0, 0, 0);
                    c3 = __builtin_amdgcn_mfma_f32_16x16x32_bf16(af0, bfrB[0][nt], c3, 0, 0, 0);
                    c3 = __builtin_amdgcn_mfma_f32_16x16x32_bf16(af1, bfrB[1][nt], c3, 0, 0, 0);
                    int col = nt * 16 + ln;
#pragma unroll
                    for (int r = 0; r < 4; r++) {
                        int row = row0 + rt * 16 + quad * 4 + r;
                        if (row < NNODES)
                            Tw[(size_t)row * DD + col] =
                                pack2(c2[r], __expf(-c3[r]));
                    }
                }
            }
        }
    };

    // Pipelined tile loop (double-buffered x in the reclaimed weight LDS).
    stage_store(lsd, tid, xa, xb);
    int tn = t + GMM;
    if (tn < NGB)
        stage_load<MODE>(tn, tid, bfflag, u, v, A, abs_s, xa, xb);
    __syncthreads();
    int buf = 0;
    while (true) {
        compute(lsd + buf * 4608, t * DD);
        if (tn >= NGB) break;
        t = tn;
        tn += GMM;
        stage_store(lsd + (buf ^ 1) * 4608, tid, xa, xb);
        if (tn < NGB)
            stage_load<MODE>(tn, tid, bfflag, u, v, A, abs_s, xa, xb);
        __syncthreads();
        buf ^= 1;
    }
}

// ---- MFMA final: out = relu(ab*A + ab' + x_in@R); wave w = rowtile w.
// ab computed in-block from SHARDED red2 counters (fused k_stats).
// bf16 output is LDS-staged (Wls reused) for full-line stores; f32 output
// already writes full 64-B lines (4B/lane x 16 lanes) -> direct.
__global__ __launch_bounds__(256) void k_final_mfma(
    const unsigned short* __restrict__ A, const float* __restrict__ red,
    const void* __restrict__ gm, const void* __restrict__ bt,
    const void* __restrict__ u, const void* __restrict__ v,
    const void* __restrict__ R, const int* __restrict__ flag,
    void* __restrict__ out)
{
    __shared__ __align__(16) unsigned short Wls[DD][72];
    __shared__ __align__(16) unsigned short xls[DD][72];
    __shared__ __align__(16) float abf[128];
    const int bfflag = flag[0];
    const int tid = threadIdx.x;
    if (tid < 64) {
        float sm = 0.f, sq = 0.f;
#pragma unroll 8
        for (int s = 0; s < NSH; s++) {
            sm += red[s * 256 + tid];
            sq += red[s * 256 + 128 + tid];
        }
        float mean = sm * (1.f / NNODES);
        float var = sq * (1.f / NNODES) - mean * mean;
        float a = ldf(gm, tid, bfflag) * rsqrtf(var + 1e-3f);
        abf[tid] = a;
        abf[64 + tid] = ldf(bt, tid, bfflag) - mean * a;
    }
    if (bfflag) {
        for (int i = tid; i < 512; i += 256) {
            int e0 = i * 8;
            *(uint4*)&Wls[e0 >> 6][e0 & 63] = ((const uint4*)R)[i];
        }
    } else {
        for (int i = tid; i < 1024; i += 256) {
            int e0 = i * 4;
            float4 f = ((const float4*)R)[i];
            *(uint2*)&Wls[e0 >> 6][e0 & 63] =
                make_uint2(pack2(f.x, f.y), pack2(f.z, f.w));
        }
    }
    uint4 w0, w1;
    stage_load<0>(blockIdx.x, tid, bfflag, u, v, nullptr, nullptr, w0, w1);
    stage_store(&xls[0][0], tid, w0, w1);
    __syncthreads();

    const int row0 = blockIdx.x * DD;
    const int wv = tid >> 6, lane = tid & 63;
    const int quad = lane >> 4, ln = lane & 15;
    bf16x8 bfr[2][4];
#pragma unroll
    for (int ks = 0; ks < 2; ks++)
#pragma unroll
        for (int nt = 0; nt < 4; nt++)
#pragma unroll
            for (int j = 0; j < 8; j++)
                bfr[ks][nt][j] = (short)Wls[ks * 32 + quad * 8 + j][nt * 16 + ln];
    float av[4], bv[4];
#pragma unroll
    for (int nt = 0; nt < 4; nt++) {
        av[nt] = abf[nt * 16 + ln];
        bv[nt] = abf[64 + nt * 16 + ln];
    }
    const int rt = wv;
    int m = rt * 16 + ln;
    bf16x8 af0 = *(const bf16x8*)&xls[m][quad * 8];
    bf16x8 af1 = *(const bf16x8*)&xls[m][32 + quad * 8];
    // All fragments now in registers; Wls becomes the output staging tile.
    __syncthreads();
#pragma unroll
    for (int nt = 0; nt < 4; nt++) {
        f32x4 c = {0.f, 0.f, 0.f, 0.f};
        c = __builtin_amdgcn_mfma_f32_16x16x32_bf16(af0, bfr[0][nt], c, 0, 0, 0);
        c = __builtin_amdgcn_mfma_f32_16x16x32_bf16(af1, bfr[1][nt], c, 0, 0, 0);
        int col = nt * 16 + ln;
#pragma unroll
        for (int r = 0; r < 4; r++) {
            int row = row0 + rt * 16 + quad * 4 + r;
            if (row < NNODES) {
                size_t o = (size_t)row * DD + col;
                float vv = av[nt] * us2f(A[o]) + bv[nt] + c[r];
                vv = vv > 0.f ? vv : 0.f;
                if (bfflag) Wls[rt * 16 + quad * 4 + r][col] = fbits(vv);
                else        ((float*)out)[o] = vv;
            }
        }
    }
    if (bfflag) {
        __syncthreads();
        // 2 passes x 256 threads x 16 B = the full 64x128-B tile, full lines.
#pragma unroll
        for (int p = 0; p < 2; p++) {
            int ci = p * 256 + tid;          // chunk id: 64 rows x 8 chunks
            int lr = ci >> 3, c8 = ci & 7;
            int row = row0 + lr;
            uint4 vv = *(const uint4*)&Wls[lr][c8 * 8];
            if (row < NNODES)
                *(uint4*)&((unsigned short*)out)[(size_t)row * DD + c8 * 8] = vv;
        }
    }
}

// ---- Gather-accumulate: 4 nodes per wave, pair-interleaved gathers +
// fused column sum/sumsq reduction with NSH-way sharded atomics.
// At its structural floor (~50 µs): three MLP probes (r7 header batch,
// r9 pair-interleave, r4 2-node) all null -> bound by L3/fabric random-64B
// service rate on the 256 MB logical gather (124.6 MB L2-miss @ ~2.8 TB/s).
// srcidx wave-uniform -> s_load + scalar-base gathers (round-1 lesson).
__global__ __launch_bounds__(256) void k_accum(
    const int* __restrict__ rowptr, const int* __restrict__ srcidx,
    const unsigned* __restrict__ T, const bf16* __restrict__ Ed,
    unsigned short* __restrict__ A, float* __restrict__ red)
{
    __shared__ float s1[256], s2[256];
    const int wv = threadIdx.x >> 6, c = threadIdx.x & 63;
    const int d0 = blockIdx.x * 16 + wv * 4;  // grid 6250 -> d0 in [0,100000)
    int rp0 = rowptr[d0], rp1 = rowptr[d0 + 1], rp2 = rowptr[d0 + 2],
        rp3 = rowptr[d0 + 3], rp4 = rowptr[d0 + 4];
    size_t o0 = (size_t)d0 * DD + c;
    float edA = b2f(Ed[o0]),       edB = b2f(Ed[o0 + 64]),
          edC = b2f(Ed[o0 + 128]), edD = b2f(Ed[o0 + 192]);
    float sA = us2f(A[o0]),       sB = us2f(A[o0 + 64]),
          sC = us2f(A[o0 + 128]), sD = us2f(A[o0 + 192]);

#define EDGE(sv, edv, tv) sv += lo_bf16(tv) * \
    __builtin_amdgcn_rcpf(1.f + edv * hi_bf16(tv));
#define NODE_TAIL(sv, edv, i, r1)                                   \
    {                                                               \
        for (; i + 3 < r1; i += 4) {                                \
            unsigned t0 = T[(size_t)srcidx[i] * DD + c];            \
            unsigned t1 = T[(size_t)srcidx[i + 1] * DD + c];        \
            unsigned t2 = T[(size_t)srcidx[i + 2] * DD + c];        \
            unsigned t3 = T[(size_t)srcidx[i + 3] * DD + c];        \
            EDGE(sv, edv, t0) EDGE(sv, edv, t1)                     \
            EDGE(sv, edv, t2) EDGE(sv, edv, t3)                     \
        }                                                           \
        for (; i < r1; i++) {                                       \
            unsigned t0 = T[(size_t)srcidx[i] * DD + c];            \
            EDGE(sv, edv, t0)                                       \
        }                                                           \
    }
#define PAIR_LOOP(sX, edX, x0, x1, sY, edY, y0, y1)                 \
    {                                                               \
        int iX = x0, iY = y0;                                       \
        while (iX + 3 < x1 && iY + 3 < y1) {                        \
            unsigned a0 = T[(size_t)srcidx[iX] * DD + c];           \
            unsigned a1 = T[(size_t)srcidx[iX + 1] * DD + c];       \
            unsigned a2 = T[(size_t)srcidx[iX + 2] * DD + c];       \
            unsigned a3 = T[(size_t)srcidx[iX + 3] * DD + c];       \
            unsigned b0 = T[(size_t)srcidx[iY] * DD + c];           \
            unsigned b1 = T[(size_t)srcidx[iY + 1] * DD + c];       \
            unsigned b2 = T[(size_t)srcidx[iY + 2] * DD + c];       \
            unsigned b3 = T[(size_t)srcidx[iY + 3] * DD + c];       \
            EDGE(sX, edX, a0) EDGE(sX, edX, a1)                     \
            EDGE(sX, edX, a2) EDGE(sX, edX, a3)                     \
            EDGE(sY, edY, b0) EDGE(sY, edY, b1)                     \
            EDGE(sY, edY, b2) EDGE(sY, edY, b3)                     \
            iX += 4; iY += 4;                                       \
        }                                                           \
        NODE_TAIL(sX, edX, iX, x1)                                  \
        NODE_TAIL(sY, edY, iY, y1)                                  \
    }

    PAIR_LOOP(sA, edA, rp0, rp1, sB, edB, rp1, rp2)
    A[o0] = fbits(sA);
    A[o0 + 64] = fbits(sB);
    PAIR_LOOP(sC, edC, rp2, rp3, sD, edD, rp3, rp4)
    A[o0 + 128] = fbits(sC);
    A[o0 + 192] = fbits(sD);
#undef PAIR_LOOP
#undef NODE_TAIL
#undef EDGE

    // fused k_reduce: block partial -> one sharded atomic per counter.
    s1[threadIdx.x] = (sA + sB) + (sC + sD);
    s2[threadIdx.x] = (sA * sA + sB * sB) + (sC * sC + sD * sD);
    __syncthreads();
    if (threadIdx.x < 64) {
        float a = s1[c] + s1[64 + c] + s1[128 + c] + s1[192 + c];
        float b = s2[c] + s2[64 + c] + s2[128 + c] + s2[192 + c];
        float* sh = red + (blockIdx.x & (NSH - 1)) * 256;
        unsafeAtomicAdd(&sh[c], a);
        unsafeAtomicAdd(&sh[128 + c], b);
    }
}

extern "C" void kernel_launch(void* const* d_in, const int* in_sizes, int n_in,
                              void* d_out, int out_size, void* d_ws, size_t ws_size,
                              hipStream_t stream)
{
    const void* u   = d_in[0];
    const void* v   = d_in[1];
    const int* es   = (const int*)d_in[2];
    const int* ee   = (const int*)d_in[3];
    const void* Ui1 = d_in[4];
    const void* Uj1 = d_in[5];
    const void* Vi1 = d_in[6];
    const void* Vj1 = d_in[7];
    const void* bu1 = d_in[8];
    const void* bv1 = d_in[9];
    const void* Ui2 = d_in[10];
    const void* Uj2 = d_in[11];
    const void* Vi2 = d_in[12];
    const void* Vj2 = d_in[13];
    const void* bu2 = d_in[14];
    const void* bv2 = d_in[15];
    const void* R   = d_in[16];
    const void* g1  = d_in[17];
    const void* be1 = d_in[18];
    const void* g2  = d_in[19];
    const void* be2 = d_in[20];
    const int E = in_sizes[2];

    // Workspace (~56.8 MB; proven round-7 layout).
    // ebuf aliases T (CSR build fully precedes k_mm4<0>'s T writes).
    // bh (400 KB) aliases srcidx (bh dead before k_group writes srcidx).
    // Ed lives in d_out until k_final overwrites it.
    // Sharded red counters (2 x 64 KB) in the srcidx..rowptr hole.
    char* ws = (char*)d_ws;
    unsigned short* A = (unsigned short*)(ws);      // 12.8 MB bf16 accumulator
    unsigned* T    = (unsigned*)(ws + 25600000);    // 25.6 MB (Ui | exp(-Vj)<<16)
    unsigned* ebuf = (unsigned*)(ws + 25600000);    // 4 MB, aliases T
    int* srcidx    = (int*)(ws + 51200000);         // 4 MB (ends 55,200,000)
    int* bh        = (int*)(ws + 51200000);         // 400 KB, aliases srcidx
    float* redsh   = (float*)(ws + 55200000);       // 128 KB sharded counters
    int* rowptr    = (int*)(ws + 56000000);         // 400,004 B
    int* flag      = (int*)(ws + 56804224);
    int* bbase     = (int*)(ws + 56805376);         // 256 ints (ends 56806400)
    int* bcursor   = (int*)(ws + 56806400);         // 256 ints
    float* red1 = redsh;                  // NSH shards x 256 floats
    float* red2 = redsh + NSH * 256;      // NSH shards x 256 floats
    bf16* Ed = (bf16*)d_out;

    // ---- CSR build (round-7 proven: sniff in bhist, parallel bscan,
    // atomic-bcursor bscatter) ----
    k_bhist<<<NBH, 256, 0, stream>>>(ee, (const unsigned short*)u, flag, bh, E);
    k_bscan<<<1, 1024, 0, stream>>>(bh, bbase, bcursor, redsh);
    k_bscatter<<<(E + ESB - 1) / ESB, 256, 0, stream>>>(es, ee, bcursor, ebuf, E);
    k_group<<<NBUK, 256, 0, stream>>>(bbase, ebuf, rowptr, srcidx);

    // ---- stage 1 ----
    k_mm4_mfma<0><<<GMM, 256, 0, stream>>>(u, v, nullptr, nullptr, nullptr,
                                           Uj1, Vi1, Ui1, Vj1, bu1, bv1, flag,
                                           A, (unsigned short*)Ed, T);
    k_accum<<<NNODES / 16, 256, 0, stream>>>(rowptr, srcidx, T, Ed, A, red1);

    // ---- stage 2 (BN1+relu fused into staging; stats fused into k_mm4) ----
    k_mm4_mfma<1><<<GMM, 256, 0, stream>>>(nullptr, nullptr, red1, g1, be1,
                                           Uj2, Vi2, Ui2, Vj2, bu2, bv2, flag,
                                           A, (unsigned short*)Ed, T);
    k_accum<<<NNODES / 16, 256, 0, stream>>>(rowptr, srcidx, T, Ed, A, red2);

    // ---- BN2 + residual (x_in@R via MFMA) + relu -> out ----
    k_final_mfma<<<NGB, 256, 0, stream>>>(A, red2, g2, be2, u, v, R, flag, d_out);
}